// Round 4
// baseline (64.418 us; speedup 1.0000x reference)
//
#include <hip/hip_runtime.h>
#include <hip/hip_bf16.h>

#define F_DIM 64
#define B_DIM 64
#define C_DIM 1024
#define BM 64
#define BN 64
#define BK 64
#define NT (C_DIM / BK)   // 16 K-steps
#define NTILES (C_DIM / BN)   // 16 o-tiles per feature

using f32x4  = __attribute__((ext_vector_type(4))) float;
using bf16x8 = __attribute__((ext_vector_type(8))) short;
using s16x4  = __attribute__((ext_vector_type(4))) short;

// fp32 -> bf16 round-to-nearest-even
static __device__ __forceinline__ short f2bf(float f) {
    unsigned u = __float_as_uint(f);
    unsigned r = (u + 0x7fffu + ((u >> 16) & 1u)) >> 16;
    return (short)r;
}

__global__ __launch_bounds__(256, 4)
void channelfc_kernel(const float* __restrict__ x,
                      const float* __restrict__ w,
                      const float* __restrict__ bias,
                      float* __restrict__ out)
{
    // R4 structure: BN=64 -> 1024 blocks -> 4 blocks/CU (16 waves/CU), fixing
    // the R2/R3 limiter: grid of 512 gave only 2 blocks/CU, so per-K-step
    // barrier stalls (gated on slowest HBM load) had only one other block to
    // hide under. 4 independent barrier domains/CU double latency cover.
    //
    // T1 XCD swizzle: block n -> XCD n%8; XCD x owns features {x, x+8, ...},
    // the 16 o-tiles of one f consecutive -> X_f (262 KB) L2-resident.
    const int n    = blockIdx.x;       // 0..1023
    const int xcd  = n & 7;
    const int j    = n >> 3;           // 0..127 within this XCD
    const int f    = xcd + 8 * (j >> 4);
    const int bx   = j & 15;           // o-tile index
    const int ocol0 = bx * BN;

    const int tid   = threadIdx.x;
    const int lane  = tid & 63;
    const int wid   = tid >> 6;
    const int wr    = wid >> 1;   // wave M half (0..1) -> rows wr*32..+32
    const int wc    = wid & 1;    // wave N half (0..1) -> cols wc*32..+32

    // bf16 tiles, T2 XOR swizzle: (row, byte) lives at row*128 + (byte ^ ((row&7)<<4))
    __shared__ short sA[2][BM * BK];   // 8 KB per buffer (X tile: row = b, col = k)
    __shared__ short sB[2][BN * BK];   // 8 KB per buffer (W tile: row = o, col = k)

    const float* xA = x + (size_t)f * C_DIM;                       // + b*(F*C) + c
    const float* wB = w + ((size_t)f * C_DIM + ocol0) * C_DIM;     // + o*C + c

    f32x4 ra[4];   // X staging: 1024 float4 / 256 thr = 4 each
    f32x4 rb[4];   // W staging: 1024 float4 / 256 thr = 4 each

    auto load_tile = [&](int t) {
        const int k0 = t * BK;
        #pragma unroll
        for (int i = 0; i < 4; ++i) {
            int id = i * 256 + tid, row = id >> 4, k4 = id & 15;   // 16 float4 per row
            ra[i] = *(const f32x4*)(xA + (size_t)row * (F_DIM * C_DIM) + k0 + k4 * 4);
            rb[i] = *(const f32x4*)(wB + (size_t)row * C_DIM + k0 + k4 * 4);
        }
    };

    auto store_tile = [&](int buf) {
        #pragma unroll
        for (int i = 0; i < 4; ++i) {
            int id = i * 256 + tid, row = id >> 4, k4 = id & 15;
            int byte = (k4 * 8) ^ ((row & 7) << 4);                // 8B store, swizzle 16B-granular
            s16x4 va; va[0]=f2bf(ra[i][0]); va[1]=f2bf(ra[i][1]); va[2]=f2bf(ra[i][2]); va[3]=f2bf(ra[i][3]);
            *(s16x4*)((char*)&sA[buf][0] + row * 128 + byte) = va;
            s16x4 vb; vb[0]=f2bf(rb[i][0]); vb[1]=f2bf(rb[i][1]); vb[2]=f2bf(rb[i][2]); vb[3]=f2bf(rb[i][3]);
            *(s16x4*)((char*)&sB[buf][0] + row * 128 + byte) = vb;
        }
    };

    f32x4 acc[2][2] = {};   // wave sub-tile 32x32 = 2 M-frags x 2 N-frags

    auto compute = [&](int buf) {
        #pragma unroll
        for (int ks = 0; ks < 2; ++ks) {
            const int kbyte = ks * 64 + (lane >> 4) * 16;   // frag: k = ks*32 + (lane>>4)*8 + j
            bf16x8 af[2], bfr[2];
            #pragma unroll
            for (int mt = 0; mt < 2; ++mt) {
                int row = wr * 32 + mt * 16 + (lane & 15);
                af[mt] = *(const bf16x8*)((const char*)&sA[buf][0] + row * 128 + (kbyte ^ ((row & 7) << 4)));
            }
            #pragma unroll
            for (int nt = 0; nt < 2; ++nt) {
                int row = wc * 32 + nt * 16 + (lane & 15);
                bfr[nt] = *(const bf16x8*)((const char*)&sB[buf][0] + row * 128 + (kbyte ^ ((row & 7) << 4)));
            }
            #pragma unroll
            for (int mt = 0; mt < 2; ++mt)
                #pragma unroll
                for (int nt = 0; nt < 2; ++nt)
                    acc[mt][nt] = __builtin_amdgcn_mfma_f32_16x16x32_bf16(af[mt], bfr[nt], acc[mt][nt], 0, 0, 0);
        }
    };

    // Barrier safety (1 barrier/step, 2 LDS bufs): compute(t) reads buf[t&1]
    // after barrier(t), which store(t) wrote before it; store(t+2) overwrites
    // buf[t&1] only after barrier(t+1), which follows compute(t)'s LDS reads
    // in every wave's program order (compiler drains lgkmcnt pre-barrier).
    // Note (R3 lesson): loads of t+1 have no reg dependency on store_tile(t)'s
    // waits, so the scheduler hoists them -- explicit ping-pong staging added
    // nothing but VGPRs. Single staging set, let the compiler pipeline.
    load_tile(0);
    for (int t = 0; t < NT; ++t) {
        const int buf = t & 1;
        store_tile(buf);
        if (t + 1 < NT) load_tile(t + 1);
        __syncthreads();
        compute(buf);
    }

    // Epilogue. C/D layout (m89-verified): col = lane&15 (-> o), row = (lane>>4)*4 + reg (-> b)
    const int ncol_base = ocol0 + wc * 32 + (lane & 15);
    const int mrow_base = wr * 32 + (lane >> 4) * 4;
    #pragma unroll
    for (int nt = 0; nt < 2; ++nt) {
        const int o  = ncol_base + nt * 16;
        const float bv = bias[f * C_DIM + o];
        #pragma unroll
        for (int mt = 0; mt < 2; ++mt) {
            #pragma unroll
            for (int r = 0; r < 4; ++r) {
                const int b = mrow_base + mt * 16 + r;
                out[((size_t)b * F_DIM + f) * C_DIM + o] = acc[mt][nt][r] + bv;
            }
        }
    }
}

extern "C" void kernel_launch(void* const* d_in, const int* in_sizes, int n_in,
                              void* d_out, int out_size, void* d_ws, size_t ws_size,
                              hipStream_t stream) {
    const float* x    = (const float*)d_in[0];
    const float* w    = (const float*)d_in[1];
    const float* bias = (const float*)d_in[2];
    float* out        = (float*)d_out;
    // 1024 blocks -> 4 blocks/CU; XCD-aware index decode in-kernel.
    channelfc_kernel<<<dim3(NTILES * F_DIM), dim3(256), 0, stream>>>(x, w, bias, out);
}

// Round 5
// 58.319 us; speedup vs baseline: 1.1046x; 1.1046x over previous
//
#include <hip/hip_runtime.h>
#include <hip/hip_bf16.h>

#define F_DIM 64
#define B_DIM 64
#define C_DIM 1024
#define BM 64
#define BN 128
#define BK 64
#define NT (C_DIM / BK)       // 16 K-steps
#define NTILES (C_DIM / BN)   // 8 o-tiles per feature
#define THREADS 512

using f32x4  = __attribute__((ext_vector_type(4))) float;
using bf16x8 = __attribute__((ext_vector_type(8))) short;
using s16x4  = __attribute__((ext_vector_type(4))) short;

// fp32 -> bf16 round-to-nearest-even
static __device__ __forceinline__ short f2bf(float f) {
    unsigned u = __float_as_uint(f);
    unsigned r = (u + 0x7fffu + ((u >> 16) & 1u)) >> 16;
    return (short)r;
}

__global__ __launch_bounds__(THREADS, 4)
void channelfc_kernel(const float* __restrict__ x,
                      const float* __restrict__ w,
                      const float* __restrict__ bias,
                      float* __restrict__ out)
{
    // R5: identical geometry/traffic to R2 (best, 58.7us) -- BN=128, grid 512,
    // 2 blocks/CU, same XCD swizzle, same LDS layout -- but 512 threads
    // (8 waves/block -> 16 waves/CU). Discriminates T-latency (more waves per
    // barrier domain -> better HBM latency cover -> ~50us) vs T-fetch
    // (already BW-bound with excess X refetch -> unchanged ~58us).
    //
    // T1 XCD swizzle: block n -> XCD n%8; XCD x owns features {x, x+8, ...},
    // 8 o-tiles of one f consecutive -> X_f (256 KB) fetched ~once per XCD.
    const int n    = blockIdx.x;       // 0..511
    const int xcd  = n & 7;
    const int j    = n >> 3;           // 0..63 within this XCD
    const int f    = xcd + 8 * (j >> 3);
    const int bx   = j & 7;            // o-tile index
    const int ocol0 = bx * BN;

    const int tid   = threadIdx.x;
    const int lane  = tid & 63;
    const int wid   = tid >> 6;   // 0..7
    const int wr    = wid >> 2;   // 0..1 -> rows wr*32..+32
    const int wc    = wid & 3;    // 0..3 -> cols wc*32..+32

    // bf16 tiles, T2 XOR swizzle: (row, byte) lives at row*128 + (byte ^ ((row&7)<<4))
    __shared__ short sA[2][BM * BK];   // 8 KB per buffer  (X tile: row = b, col = k)
    __shared__ short sB[2][BN * BK];   // 16 KB per buffer (W tile: row = o, col = k)

    const float* xA = x + (size_t)f * C_DIM;                       // + b*(F*C) + c
    const float* wB = w + ((size_t)f * C_DIM + ocol0) * C_DIM;     // + o*C + c

    f32x4 ra[2];   // X staging: 1024 float4 / 512 thr = 2 each
    f32x4 rb[4];   // W staging: 2048 float4 / 512 thr = 4 each

    auto load_tile = [&](int t) {
        const int k0 = t * BK;
        #pragma unroll
        for (int i = 0; i < 2; ++i) {
            int id = i * THREADS + tid, row = id >> 4, k4 = id & 15;   // 16 float4 per row
            ra[i] = *(const f32x4*)(xA + (size_t)row * (F_DIM * C_DIM) + k0 + k4 * 4);
        }
        #pragma unroll
        for (int i = 0; i < 4; ++i) {
            int id = i * THREADS + tid, row = id >> 4, k4 = id & 15;
            rb[i] = *(const f32x4*)(wB + (size_t)row * C_DIM + k0 + k4 * 4);
        }
    };

    auto store_tile = [&](int buf) {
        #pragma unroll
        for (int i = 0; i < 2; ++i) {
            int id = i * THREADS + tid, row = id >> 4, k4 = id & 15;
            int byte = (k4 * 8) ^ ((row & 7) << 4);                // 8B store, swizzle 16B-granular
            s16x4 v; v[0]=f2bf(ra[i][0]); v[1]=f2bf(ra[i][1]); v[2]=f2bf(ra[i][2]); v[3]=f2bf(ra[i][3]);
            *(s16x4*)((char*)&sA[buf][0] + row * 128 + byte) = v;
        }
        #pragma unroll
        for (int i = 0; i < 4; ++i) {
            int id = i * THREADS + tid, row = id >> 4, k4 = id & 15;
            int byte = (k4 * 8) ^ ((row & 7) << 4);
            s16x4 v; v[0]=f2bf(rb[i][0]); v[1]=f2bf(rb[i][1]); v[2]=f2bf(rb[i][2]); v[3]=f2bf(rb[i][3]);
            *(s16x4*)((char*)&sB[buf][0] + row * 128 + byte) = v;
        }
    };

    f32x4 acc[2][2] = {};   // wave sub-tile 32x32 = 2 M-frags x 2 N-frags

    auto compute = [&](int buf) {
        #pragma unroll
        for (int ks = 0; ks < 2; ++ks) {
            const int kbyte = ks * 64 + (lane >> 4) * 16;   // frag: k = ks*32 + (lane>>4)*8 + j
            bf16x8 af[2], bfr[2];
            #pragma unroll
            for (int mt = 0; mt < 2; ++mt) {
                int row = wr * 32 + mt * 16 + (lane & 15);
                af[mt] = *(const bf16x8*)((const char*)&sA[buf][0] + row * 128 + (kbyte ^ ((row & 7) << 4)));
            }
            #pragma unroll
            for (int nt = 0; nt < 2; ++nt) {
                int row = wc * 32 + nt * 16 + (lane & 15);
                bfr[nt] = *(const bf16x8*)((const char*)&sB[buf][0] + row * 128 + (kbyte ^ ((row & 7) << 4)));
            }
            #pragma unroll
            for (int mt = 0; mt < 2; ++mt)
                #pragma unroll
                for (int nt = 0; nt < 2; ++nt)
                    acc[mt][nt] = __builtin_amdgcn_mfma_f32_16x16x32_bf16(af[mt], bfr[nt], acc[mt][nt], 0, 0, 0);
        }
    };

    // Barrier safety (1 barrier/step, 2 LDS bufs): compute(t) reads buf[t&1]
    // after barrier(t), which store(t) wrote before it; store(t+2) overwrites
    // buf[t&1] only after barrier(t+1), which follows compute(t)'s LDS reads
    // in every wave's program order (compiler drains lgkmcnt pre-barrier).
    load_tile(0);
    for (int t = 0; t < NT; ++t) {
        const int buf = t & 1;
        store_tile(buf);
        if (t + 1 < NT) load_tile(t + 1);   // no reg dep on store's waits -> scheduler hoists
        __syncthreads();
        compute(buf);
    }

    // Epilogue. C/D layout (m89-verified): col = lane&15 (-> o), row = (lane>>4)*4 + reg (-> b)
    const int ncol_base = ocol0 + wc * 32 + (lane & 15);
    const int mrow_base = wr * 32 + (lane >> 4) * 4;
    #pragma unroll
    for (int nt = 0; nt < 2; ++nt) {
        const int o  = ncol_base + nt * 16;
        const float bv = bias[f * C_DIM + o];
        #pragma unroll
        for (int mt = 0; mt < 2; ++mt) {
            #pragma unroll
            for (int r = 0; r < 4; ++r) {
                const int b = mrow_base + mt * 16 + r;
                out[((size_t)b * F_DIM + f) * C_DIM + o] = acc[mt][nt][r] + bv;
            }
        }
    }
}

extern "C" void kernel_launch(void* const* d_in, const int* in_sizes, int n_in,
                              void* d_out, int out_size, void* d_ws, size_t ws_size,
                              hipStream_t stream) {
    const float* x    = (const float*)d_in[0];
    const float* w    = (const float*)d_in[1];
    const float* bias = (const float*)d_in[2];
    float* out        = (float*)d_out;
    // 512 blocks (2/CU), XCD-aware index decode in-kernel.
    channelfc_kernel<<<dim3(NTILES * F_DIM), dim3(THREADS), 0, stream>>>(x, w, bias, out);
}